// Round 14
// baseline (76.665 us; speedup 1.0000x reference)
//
#include <hip/hip_runtime.h>
#include <stdint.h>

#define NB 64      // batch rows
#define NK 1024    // keys
#define ND 512     // dim
#define ROWS 2                                  // batch rows per block
#define CHUNKS 64                               // key chunks
#define KEYS_PER_BLOCK (NK / CHUNKS)            // 16
#define WAVES_PER_BLOCK 4
#define KEYS_PER_WAVE (KEYS_PER_BLOCK / WAVES_PER_BLOCK)  // 4
#define REP 8      // DIAGNOSTIC: repeat phase-1 8x in-kernel; S=(dur-17.5)/7. LB(256,4): no spill.
// ws layout: u64 packed winner per (row, chunk): [NB][CHUNKS]

#if __has_builtin(__builtin_amdgcn_exp2f)
#define EXP2F(x) __builtin_amdgcn_exp2f(x)
#else
#define EXP2F(x) exp2f(x)
#endif
#if __has_builtin(__builtin_amdgcn_rcpf)
#define RCPF(x) __builtin_amdgcn_rcpf(x)
#else
#define RCPF(x) (1.0f / (x))
#endif

// u * sigmoid(u + 1) accumulated into acc (mask dropped; see R13 note).
__device__ __forceinline__ float silu_acc(float qc, float kv, float acc) {
    float u = qc * kv;
    const float NL2E = -1.4426950408889634f;
    float y = fmaf(u, NL2E, NL2E);      // -(u+1)*log2e
    float e = EXP2F(y);
    float r = RCPF(1.0f + e);
    return fmaf(u, r, acc);
}

// pack: [sortable_score:32][..][1023-k:10]. max() picks best score; on exact
// score ties larger (1023-k) => smaller k wins (numpy argmax first-occurrence).
// Any real pack value is > 0, so 0 is a safe "empty" under max.
__device__ __forceinline__ unsigned long long pack_win(float s, int k) {
    uint32_t bits = __float_as_uint(s);
    uint32_t so = (bits & 0x80000000u) ? ~bits : (bits | 0x80000000u);
    return ((unsigned long long)so << 32) | (unsigned long long)(uint32_t)(NK - 1 - k);
}

__global__ __launch_bounds__(256, 4) void sia_scores(const float* __restrict__ q,
                                                     const float* __restrict__ keys,
                                                     unsigned long long* __restrict__ ws) {
    const int bidx = blockIdx.x;            // 0 .. 2047
    const int bg    = bidx >> 6;            // row group 0..31
    const int chunk = bidx & (CHUNKS - 1);  // 0..63
    const int tid = threadIdx.x;
    const int wave = tid >> 6;
    const int lane = tid & 63;

    const float C = 100.0f * 0.04419417382415922f;   // SCALE * D^-0.5

    float4 qa[ROWS], qb[ROWS];
    #pragma unroll
    for (int r = 0; r < ROWS; ++r) {
        const float4* q4 = reinterpret_cast<const float4*>(q + (bg * ROWS + r) * ND + lane * 8);
        qa[r] = q4[0]; qb[r] = q4[1];
        qa[r].x *= C; qa[r].y *= C; qa[r].z *= C; qa[r].w *= C;
        qb[r].x *= C; qb[r].y *= C; qb[r].z *= C; qb[r].w *= C;
    }

    const int k0 = chunk * KEYS_PER_BLOCK + wave * KEYS_PER_WAVE;

    unsigned long long wwin[ROWS] = {0ull, 0ull};

    uintptr_t kaddr = (uintptr_t)keys;
    #pragma unroll 1
    for (int rep = 0; rep < REP; ++rep) {
        asm volatile("" : "+s"(kaddr));     // opaque: defeat CSE/DCE across reps
        const float* kbase = (const float*)kaddr;

        float acc[ROWS][KEYS_PER_WAVE];
        #pragma unroll
        for (int r = 0; r < ROWS; ++r)
            #pragma unroll
            for (int i = 0; i < KEYS_PER_WAVE; ++i)
                acc[r][i] = 0.0f;

        #pragma unroll
        for (int i = 0; i < KEYS_PER_WAVE; ++i) {
            const float4* k4 = reinterpret_cast<const float4*>(kbase + (k0 + i) * ND + lane * 8);
            float4 ka = k4[0];
            float4 kb = k4[1];
            #pragma unroll
            for (int r = 0; r < ROWS; ++r) {
                float p = acc[r][i];
                p = silu_acc(qa[r].x, ka.x, p);
                p = silu_acc(qa[r].y, ka.y, p);
                p = silu_acc(qa[r].z, ka.z, p);
                p = silu_acc(qa[r].w, ka.w, p);
                p = silu_acc(qb[r].x, kb.x, p);
                p = silu_acc(qb[r].y, kb.y, p);
                p = silu_acc(qb[r].z, kb.z, p);
                p = silu_acc(qb[r].w, kb.w, p);
                acc[r][i] = p;
            }
        }

        #pragma unroll
        for (int off = 32; off > 0; off >>= 1) {
            #pragma unroll
            for (int r = 0; r < ROWS; ++r)
                #pragma unroll
                for (int i = 0; i < KEYS_PER_WAVE; ++i)
                    acc[r][i] += __shfl_xor(acc[r][i], off, 64);
        }

        #pragma unroll
        for (int r = 0; r < ROWS; ++r) {
            float best_s = acc[r][0];
            int best_j = 0;
            #pragma unroll
            for (int i = 1; i < KEYS_PER_WAVE; ++i)
                if (acc[r][i] > best_s) { best_s = acc[r][i]; best_j = i; }
            unsigned long long pw = pack_win(best_s, k0 + best_j);
            if (pw > wwin[r]) wwin[r] = pw;   // idempotent across identical reps
        }
    }

    __shared__ unsigned long long win[WAVES_PER_BLOCK][ROWS];
    if (lane == 0) {
        #pragma unroll
        for (int r = 0; r < ROWS; ++r)
            win[wave][r] = wwin[r];
    }
    __syncthreads();

    if (tid < ROWS) {
        const int r = tid;
        unsigned long long p = win[0][r];
        #pragma unroll
        for (int w = 1; w < WAVES_PER_BLOCK; ++w)
            if (win[w][r] > p) p = win[w][r];
        ws[(bg * ROWS + r) * CHUNKS + chunk] = p;
    }
}

__global__ __launch_bounds__(128) void sia_final(const unsigned long long* __restrict__ ws,
                                                 const float* __restrict__ values,
                                                 float* __restrict__ out) {
    const int b = blockIdx.x;
    const int tid = threadIdx.x;
    const int lane = tid & 63;

    unsigned long long p = ws[b * CHUNKS + lane];
    #pragma unroll
    for (int off = 32; off > 0; off >>= 1) {
        unsigned long long o = __shfl_xor(p, off, 64);
        if (o > p) p = o;
    }
    const int k = NK - 1 - (int)((uint32_t)p & 0x3FFu);

    const float4* v4 = reinterpret_cast<const float4*>(values + (size_t)k * ND);
    float4* o4 = reinterpret_cast<float4*>(out + b * ND);
    o4[tid] = v4[tid];

    if (tid == 0)
        out[NB * ND + b] = (float)k;   // winner_idx, read back as float32
}

extern "C" void kernel_launch(void* const* d_in, const int* in_sizes, int n_in,
                              void* d_out, int out_size, void* d_ws, size_t ws_size,
                              hipStream_t stream) {
    const float* q      = (const float*)d_in[0];   // [64, 512]
    const float* keys   = (const float*)d_in[1];   // [1024, 512]
    const float* values = (const float*)d_in[2];   // [1024, 512]
    float* out = (float*)d_out;                    // 64*512 values then 64 idx
    unsigned long long* ws = (unsigned long long*)d_ws;

    sia_scores<<<dim3((NB / ROWS) * CHUNKS), dim3(256), 0, stream>>>(q, keys, ws);
    sia_final<<<dim3(NB), dim3(128), 0, stream>>>(ws, values, out);
}

// Round 15
// 16.436 us; speedup vs baseline: 4.6643x; 4.6643x over previous
//
#include <hip/hip_runtime.h>
#include <stdint.h>

#define NB 64      // batch rows
#define NK 1024    // keys
#define ND 512     // dim
#define ROWS 2                                  // batch rows per block
#define CHUNKS 64                               // key chunks
#define KEYS_PER_BLOCK (NK / CHUNKS)            // 16
#define WAVES_PER_BLOCK 4
#define KEYS_PER_WAVE (KEYS_PER_BLOCK / WAVES_PER_BLOCK)  // 4
// ws layout: u64 packed winner per (row, chunk): [NB][CHUNKS]

typedef float v2f __attribute__((ext_vector_type(2)));

#if __has_builtin(__builtin_amdgcn_exp2f)
#define EXP2F(x) __builtin_amdgcn_exp2f(x)
#else
#define EXP2F(x) exp2f(x)
#endif
#if __has_builtin(__builtin_amdgcn_rcpf)
#define RCPF(x) __builtin_amdgcn_rcpf(x)
#else
#define RCPF(x) (1.0f / (x))
#endif

// Packed silu pair with shared reciprocal:
//   u = qc*kv  (pk_mul)         y = -(u+1)*log2e  (pk_fma)
//   e = exp2(y) (2x trans)      f = 1+e           (pk_add)
//   r = rcp(f.x*f.y) (1 trans)  sig = (r*f.y, r*f.x)  == 1/f elementwise
//   acc += u*sig (pk_fma)
// Replaces 2 rcp with 1 rcp + 3 mul; sigma error ~2-3ulp -> argmax-invariant.
// Mask dropped (see R13 note): zero key elems give exactly-zero terms.
__device__ __forceinline__ void silu2_acc(v2f qc, v2f kv, v2f& acc) {
    const float NL2E = -1.4426950408889634f;
    v2f u = qc * kv;
    v2f y = u * NL2E + NL2E;
    v2f e;
    e.x = EXP2F(y.x);
    e.y = EXP2F(y.y);
    v2f f = e + 1.0f;
    float r = RCPF(f.x * f.y);
    v2f sg;
    sg.x = r * f.y;
    sg.y = r * f.x;
    acc += u * sg;
}

// pack: [sortable_score:32][..][1023-k:10]. max() picks best score; on exact
// score ties larger (1023-k) => smaller k wins (numpy argmax first-occurrence).
__device__ __forceinline__ unsigned long long pack_win(float s, int k) {
    uint32_t bits = __float_as_uint(s);
    uint32_t so = (bits & 0x80000000u) ? ~bits : (bits | 0x80000000u);
    return ((unsigned long long)so << 32) | (unsigned long long)(uint32_t)(NK - 1 - k);
}

__global__ __launch_bounds__(256, 8) void sia_scores(const float* __restrict__ q,
                                                     const float* __restrict__ keys,
                                                     unsigned long long* __restrict__ ws) {
    const int bidx = blockIdx.x;            // 0 .. 2047
    const int bg    = bidx >> 6;            // row group 0..31
    const int chunk = bidx & (CHUNKS - 1);  // 0..63
    const int tid = threadIdx.x;
    const int wave = tid >> 6;
    const int lane = tid & 63;

    const float C = 100.0f * 0.04419417382415922f;   // SCALE * D^-0.5

    // 2 rows' q fragments as 4 v2f each; lane owns dims [lane*8, lane*8+8)
    v2f qv[ROWS][4];
    #pragma unroll
    for (int r = 0; r < ROWS; ++r) {
        const v2f* q2 = reinterpret_cast<const v2f*>(q + (bg * ROWS + r) * ND + lane * 8);
        #pragma unroll
        for (int j = 0; j < 4; ++j)
            qv[r][j] = q2[j] * C;
    }

    const int k0 = chunk * KEYS_PER_BLOCK + wave * KEYS_PER_WAVE;

    v2f acc[ROWS][KEYS_PER_WAVE];
    #pragma unroll
    for (int r = 0; r < ROWS; ++r)
        #pragma unroll
        for (int i = 0; i < KEYS_PER_WAVE; ++i)
            acc[r][i] = (v2f)0.0f;

    #pragma unroll
    for (int i = 0; i < KEYS_PER_WAVE; ++i) {
        // 16B vector loads, then view as v2f pairs
        const float4* k4 = reinterpret_cast<const float4*>(keys + (k0 + i) * ND + lane * 8);
        float4 ka = k4[0];
        float4 kb = k4[1];
        v2f kv[4];
        kv[0] = (v2f){ka.x, ka.y};
        kv[1] = (v2f){ka.z, ka.w};
        kv[2] = (v2f){kb.x, kb.y};
        kv[3] = (v2f){kb.z, kb.w};
        #pragma unroll
        for (int r = 0; r < ROWS; ++r)
            #pragma unroll
            for (int j = 0; j < 4; ++j)
                silu2_acc(qv[r][j], kv[j], acc[r][i]);
    }

    // collapse v2f halves, then batched butterfly (8 independent values/step)
    float sc[ROWS][KEYS_PER_WAVE];
    #pragma unroll
    for (int r = 0; r < ROWS; ++r)
        #pragma unroll
        for (int i = 0; i < KEYS_PER_WAVE; ++i)
            sc[r][i] = acc[r][i].x + acc[r][i].y;

    #pragma unroll
    for (int off = 32; off > 0; off >>= 1) {
        #pragma unroll
        for (int r = 0; r < ROWS; ++r)
            #pragma unroll
            for (int i = 0; i < KEYS_PER_WAVE; ++i)
                sc[r][i] += __shfl_xor(sc[r][i], off, 64);
    }

    // per-wave argmax over its keys (strict >: earliest key wins ties)
    __shared__ unsigned long long win[WAVES_PER_BLOCK][ROWS];
    if (lane == 0) {
        #pragma unroll
        for (int r = 0; r < ROWS; ++r) {
            float best_s = sc[r][0];
            int best_j = 0;
            #pragma unroll
            for (int i = 1; i < KEYS_PER_WAVE; ++i)
                if (sc[r][i] > best_s) { best_s = sc[r][i]; best_j = i; }
            win[wave][r] = pack_win(best_s, k0 + best_j);
        }
    }
    __syncthreads();

    // cross-wave reduce (packed max also resolves index ties to smaller k)
    if (tid < ROWS) {
        const int r = tid;
        unsigned long long p = win[0][r];
        #pragma unroll
        for (int w = 1; w < WAVES_PER_BLOCK; ++w)
            if (win[w][r] > p) p = win[w][r];
        ws[(bg * ROWS + r) * CHUNKS + chunk] = p;
    }
}

__global__ __launch_bounds__(128) void sia_final(const unsigned long long* __restrict__ ws,
                                                 const float* __restrict__ values,
                                                 float* __restrict__ out) {
    const int b = blockIdx.x;
    const int tid = threadIdx.x;
    const int lane = tid & 63;

    // both waves redundantly reduce (avoids a barrier)
    unsigned long long p = ws[b * CHUNKS + lane];
    #pragma unroll
    for (int off = 32; off > 0; off >>= 1) {
        unsigned long long o = __shfl_xor(p, off, 64);
        if (o > p) p = o;
    }
    const int k = NK - 1 - (int)((uint32_t)p & 0x3FFu);

    // gather winner's values row: 128 threads x 16B = 2KB
    const float4* v4 = reinterpret_cast<const float4*>(values + (size_t)k * ND);
    float4* o4 = reinterpret_cast<float4*>(out + b * ND);
    o4[tid] = v4[tid];

    if (tid == 0)
        out[NB * ND + b] = (float)k;   // winner_idx, read back as float32
}

extern "C" void kernel_launch(void* const* d_in, const int* in_sizes, int n_in,
                              void* d_out, int out_size, void* d_ws, size_t ws_size,
                              hipStream_t stream) {
    const float* q      = (const float*)d_in[0];   // [64, 512]
    const float* keys   = (const float*)d_in[1];   // [1024, 512]
    const float* values = (const float*)d_in[2];   // [1024, 512]
    float* out = (float*)d_out;                    // 64*512 values then 64 idx
    unsigned long long* ws = (unsigned long long*)d_ws;

    sia_scores<<<dim3((NB / ROWS) * CHUNKS), dim3(256), 0, stream>>>(q, keys, ws);
    sia_final<<<dim3(NB), dim3(128), 0, stream>>>(ws, values, out);
}